// Round 1
// baseline (2111.029 us; speedup 1.0000x reference)
//
#include <hip/hip_runtime.h>
#include <cstdint>
#include <cstddef>

#define TT 1024
#define BB 256
#define II 128
#define HH 256
#define GG 768
#define OO 64
#define TCH 256            // timesteps per chunk
#define NCH (TT / TCH)

typedef float f32x4 __attribute__((ext_vector_type(4)));
typedef short short8 __attribute__((ext_vector_type(8)));

__device__ __forceinline__ unsigned f2bf(float f) {
  unsigned u = __builtin_bit_cast(unsigned, f);
  return (u + 0x7FFFu + ((u >> 16) & 1u)) >> 16;   // RNE
}
__device__ __forceinline__ float bf2f(unsigned s) {
  return __builtin_bit_cast(float, s << 16);
}
__device__ __forceinline__ float sigm(float x) {
  return __builtin_amdgcn_rcpf(1.f + __builtin_amdgcn_exp2f(-1.44269504088896f * x));
}
__device__ __forceinline__ float tanhx(float x) {
  // tanh(x) = 1 - 2/(1 + e^{2x});  e^{2x} = 2^{2x*log2(e)}
  return 1.f - 2.f * __builtin_amdgcn_rcpf(1.f + __builtin_amdgcn_exp2f(2.88539008177793f * x));
}

// ---------------- b_total: b_ih + (b_hh for r,z gates only) ----------------
__global__ void k_btot(const float* __restrict__ bih, const float* __restrict__ bhh,
                       float* __restrict__ btot) {
  int i = blockIdx.x * 256 + threadIdx.x;
  if (i < GG) btot[i] = bih[i] + (i < 512 ? bhh[i] : 0.f);
}

// ---------------- phase 1: xg (input projections), fragment-order bf16 ------
// layout: record[(tl*16+mt)*8+wv)*3+g3][lane] = 16B = 8 bf16:
//   s[th*4+r] = xg value for batch row (wg*16 + quad*4 + r), unit wv*32+th*16+cu
__global__ __launch_bounds__(512) void k_xg(const float* __restrict__ x,
    const float* __restrict__ Wih, const float* __restrict__ btot,
    unsigned short* __restrict__ xg, int t0)
{
  __shared__ unsigned short xlds[BB * II];   // 64KB, swizzled bf16 of x[:, t, :]
  const int tid = threadIdx.x;
  const int tl = blockIdx.x;
  const int tg = t0 + tl;
  const int wv8 = tid >> 6, lane = tid & 63, cu = lane & 15, quad = lane >> 4;

  // stage x[:, tg, :] -> LDS bf16 (swizzled rows of 256B)
  for (int i = 0; i < 16; ++i) {
    int cid = tid + i * 512;          // 8192 16B-chunks (256 rows x 32)
    int row = cid >> 5, c16 = cid & 31;
    const float4 v = *(const float4*)(x + (size_t)row * TT * II + (size_t)tg * II + c16 * 4);
    unsigned lo = f2bf(v.x) | (f2bf(v.y) << 16);
    unsigned hi = f2bf(v.z) | (f2bf(v.w) << 16);
    int byt = (row * 256 + c16 * 8) ^ ((row & 7) << 4);
    *(uint2*)((char*)xlds + byt) = make_uint2(lo, hi);
  }
  __syncthreads();

  #pragma unroll
  for (int j = 0; j < 3; ++j) {
    int p = wv8 * 3 + j;
    int wvv = p / 3, g3 = p % 3;
    uint4 Wf[2][4];
    float bt2[2];
    #pragma unroll
    for (int th = 0; th < 2; ++th) {
      int row = g3 * 256 + wvv * 32 + th * 16 + cu;
      const float4* wr = (const float4*)(Wih + (size_t)row * II);
      #pragma unroll
      for (int kk = 0; kk < 4; ++kk) {
        float4 lo = wr[kk * 8 + quad * 2];
        float4 hi = wr[kk * 8 + quad * 2 + 1];
        uint4 pk;
        pk.x = f2bf(lo.x) | (f2bf(lo.y) << 16);
        pk.y = f2bf(lo.z) | (f2bf(lo.w) << 16);
        pk.z = f2bf(hi.x) | (f2bf(hi.y) << 16);
        pk.w = f2bf(hi.z) | (f2bf(hi.w) << 16);
        Wf[th][kk] = pk;
      }
      bt2[th] = btot[row];
    }
    #pragma unroll 1
    for (int pass = 0; pass < 4; ++pass) {
      f32x4 acc[4][2];
      short8 af[4][4];
      #pragma unroll
      for (int mm = 0; mm < 4; ++mm) {
        int row = (pass * 4 + mm) * 16 + cu;
        #pragma unroll
        for (int kk = 0; kk < 4; ++kk) {
          int byt = (row * 256 + kk * 64 + quad * 16) ^ ((row & 7) << 4);
          af[mm][kk] = *(const short8*)((const char*)xlds + byt);
        }
        acc[mm][0] = (f32x4){0.f, 0.f, 0.f, 0.f};
        acc[mm][1] = (f32x4){0.f, 0.f, 0.f, 0.f};
      }
      #pragma unroll
      for (int kk = 0; kk < 4; ++kk)
        #pragma unroll
        for (int mm = 0; mm < 4; ++mm)
          #pragma unroll
          for (int th = 0; th < 2; ++th)
            acc[mm][th] = __builtin_amdgcn_mfma_f32_16x16x32_bf16(
                af[mm][kk], __builtin_bit_cast(short8, Wf[th][kk]), acc[mm][th], 0, 0, 0);
      #pragma unroll
      for (int mm = 0; mm < 4; ++mm) {
        int mt = pass * 4 + mm;
        uint4 o;
        o.x = f2bf(acc[mm][0][0] + bt2[0]) | (f2bf(acc[mm][0][1] + bt2[0]) << 16);
        o.y = f2bf(acc[mm][0][2] + bt2[0]) | (f2bf(acc[mm][0][3] + bt2[0]) << 16);
        o.z = f2bf(acc[mm][1][0] + bt2[1]) | (f2bf(acc[mm][1][1] + bt2[1]) << 16);
        o.w = f2bf(acc[mm][1][2] + bt2[1]) | (f2bf(acc[mm][1][3] + bt2[1]) << 16);
        size_t rec = ((((size_t)tl * 16 + mt) * 8 + wvv) * 3 + g3) * 64 + lane;
        *(uint4*)(xg + rec * 8) = o;
      }
    }
  }
}

// ---------------- phase 2: the sequential scan (16 WGs, W_hh in registers) --
__global__ __launch_bounds__(512) void k_scan(const float* __restrict__ Whh,
    const float* __restrict__ bhh, const float* __restrict__ alpha,
    const unsigned short* __restrict__ xg, float* __restrict__ hlast, int t0)
{
  __shared__ unsigned short hbuf[2][16 * 256];  // 16KB h double-buffer (swizzled)
  __shared__ uint4 wlds[8][6][64];              // 48KB: W_hh kk=7 fragments
  const int tid = threadIdx.x, wv = tid >> 6, lane = tid & 63;
  const int cu = lane & 15, quad = lane >> 4;
  const int wg = blockIdx.x;

  // --- W_hh -> bf16 B-fragments (kk 0..6 in regs, kk 7 in LDS)
  uint4 Wf[6][7];
  float asig[2], bh2[2];
  #pragma unroll
  for (int g3 = 0; g3 < 3; ++g3)
    #pragma unroll
    for (int th = 0; th < 2; ++th) {
      int row = g3 * 256 + wv * 32 + th * 16 + cu;
      const float4* wr = (const float4*)(Whh + (size_t)row * HH);
      #pragma unroll
      for (int kk = 0; kk < 8; ++kk) {
        float4 lo = wr[kk * 8 + quad * 2];
        float4 hi = wr[kk * 8 + quad * 2 + 1];
        uint4 pk;
        pk.x = f2bf(lo.x) | (f2bf(lo.y) << 16);
        pk.y = f2bf(lo.z) | (f2bf(lo.w) << 16);
        pk.z = f2bf(hi.x) | (f2bf(hi.y) << 16);
        pk.w = f2bf(hi.z) | (f2bf(hi.w) << 16);
        if (kk < 7) Wf[g3 * 2 + th][kk] = pk;
        else        wlds[wv][g3 * 2 + th][lane] = pk;
      }
    }
  #pragma unroll
  for (int th = 0; th < 2; ++th) {
    int u = wv * 32 + th * 16 + cu;
    asig[th] = sigm(alpha[u]);
    bh2[th] = bhh[512 + u];
  }
  // --- h init (zeros for first chunk, else carried h from d_ws)
  for (int i = 0; i < 8; ++i) {
    int idx = tid * 8 + i;            // 4096 = 16 rows x 256 units
    int m = idx >> 8, u = idx & 255;
    float hv = (t0 == 0) ? 0.f : hlast[((size_t)wg * 16 + m) * 256 + u];
    int byt = (m * 512 + u * 2) ^ ((m & 7) << 4);
    *(unsigned short*)((char*)hbuf[0] + byt) = (unsigned short)f2bf(hv);
  }
  __syncthreads();

  const uint4* xgq = (const uint4*)xg;
  size_t base0 = (((size_t)wg) * 8 + wv) * 3 * 64 + lane;
  uint4 q0 = xgq[base0], q1 = xgq[base0 + 64], q2 = xgq[base0 + 128];

  int cur = 0;
  for (int tl = 0; tl < TCH; ++tl) {
    // ---- acc init from xg (consumes q*, frees them for prefetch)
    f32x4 acc[6];
    float xgn[2][4];
    acc[0][0] = bf2f(q0.x & 0xffffu); acc[0][1] = bf2f(q0.x >> 16);
    acc[0][2] = bf2f(q0.y & 0xffffu); acc[0][3] = bf2f(q0.y >> 16);
    acc[1][0] = bf2f(q0.z & 0xffffu); acc[1][1] = bf2f(q0.z >> 16);
    acc[1][2] = bf2f(q0.w & 0xffffu); acc[1][3] = bf2f(q0.w >> 16);
    acc[2][0] = bf2f(q1.x & 0xffffu); acc[2][1] = bf2f(q1.x >> 16);
    acc[2][2] = bf2f(q1.y & 0xffffu); acc[2][3] = bf2f(q1.y >> 16);
    acc[3][0] = bf2f(q1.z & 0xffffu); acc[3][1] = bf2f(q1.z >> 16);
    acc[3][2] = bf2f(q1.w & 0xffffu); acc[3][3] = bf2f(q1.w >> 16);
    xgn[0][0] = bf2f(q2.x & 0xffffu); xgn[0][1] = bf2f(q2.x >> 16);
    xgn[0][2] = bf2f(q2.y & 0xffffu); xgn[0][3] = bf2f(q2.y >> 16);
    xgn[1][0] = bf2f(q2.z & 0xffffu); xgn[1][1] = bf2f(q2.z >> 16);
    xgn[1][2] = bf2f(q2.w & 0xffffu); xgn[1][3] = bf2f(q2.w >> 16);
    acc[4] = (f32x4){bh2[0], bh2[0], bh2[0], bh2[0]};
    acc[5] = (f32x4){bh2[1], bh2[1], bh2[1], bh2[1]};

    // ---- prefetch next step's xg (1 ahead; HBM latency hidden under MFMAs)
    {
      int tn = (tl < TCH - 1) ? tl + 1 : tl;
      size_t bn = ((((size_t)tn * 16 + wg)) * 8 + wv) * 3 * 64 + lane;
      q0 = xgq[bn]; q1 = xgq[bn + 64]; q2 = xgq[bn + 128];
    }

    // ---- gh = h @ W_hh^T  (48 MFMAs/wave)
    const char* hs = (const char*)hbuf[cur];
    #pragma unroll
    for (int kk = 0; kk < 7; ++kk) {
      short8 af = *(const short8*)(hs + ((cu * 512 + kk * 64 + quad * 16) ^ ((cu & 7) << 4)));
      #pragma unroll
      for (int nt = 0; nt < 6; ++nt)
        acc[nt] = __builtin_amdgcn_mfma_f32_16x16x32_bf16(
            af, __builtin_bit_cast(short8, Wf[nt][kk]), acc[nt], 0, 0, 0);
    }
    {
      short8 af = *(const short8*)(hs + ((cu * 512 + 7 * 64 + quad * 16) ^ ((cu & 7) << 4)));
      #pragma unroll
      for (int nt = 0; nt < 6; ++nt) {
        short8 wf = __builtin_bit_cast(short8, wlds[wv][nt][lane]);
        acc[nt] = __builtin_amdgcn_mfma_f32_16x16x32_bf16(af, wf, acc[nt], 0, 0, 0);
      }
    }

    // ---- gates + h update (per-lane; C-layout col=cu, row=quad*4+r)
    char* hd = (char*)hbuf[cur ^ 1];
    bool cend = (tl == TCH - 1);
    #pragma unroll
    for (int th = 0; th < 2; ++th) {
      int u = wv * 32 + th * 16 + cu;
      #pragma unroll
      for (int r = 0; r < 4; ++r) {
        int m = quad * 4 + r;
        int hb = (m * 512 + u * 2) ^ ((m & 7) << 4);
        float hp = bf2f(*(const unsigned short*)(hs + hb));
        float rr = sigm(acc[0 + th][r]);
        float zz = sigm(acc[2 + th][r]);
        float nn = tanhx(xgn[th][r] + rr * acc[4 + th][r]);
        float hnew = nn + zz * (hp - nn);
        float hout = hp + asig[th] * (hnew - hp);
        *(unsigned short*)(hd + hb) = (unsigned short)f2bf(hout);
        if (cend) hlast[((size_t)wg * 16 + m) * 256 + u] = hout;
      }
    }
    __syncthreads();
    cur ^= 1;
  }
}

// ---------------- phase 3: out = sigmoid(h_last @ fc_w^T + fc_b) ------------
__global__ void k_out(const float* __restrict__ hlast, const float* __restrict__ fcw,
                      const float* __restrict__ fcb, float* __restrict__ out)
{
  int g = blockIdx.x * 256 + threadIdx.x;   // 16384 outputs
  int b = g >> 6, o = g & 63;
  const float* hr = hlast + (size_t)b * HH;
  const float* wr = fcw + (size_t)o * HH;
  float acc = fcb[o];
  for (int u = 0; u < HH; ++u) acc = fmaf(hr[u], wr[u], acc);
  out[g] = sigm(acc);
}

extern "C" void kernel_launch(void* const* d_in, const int* in_sizes, int n_in,
                              void* d_out, int out_size, void* d_ws, size_t ws_size,
                              hipStream_t stream)
{
  const float* x   = (const float*)d_in[0];
  const float* Wih = (const float*)d_in[1];
  const float* Whh = (const float*)d_in[2];
  const float* bih = (const float*)d_in[3];
  const float* bhh = (const float*)d_in[4];
  const float* alp = (const float*)d_in[5];
  const float* fcw = (const float*)d_in[6];
  const float* fcb = (const float*)d_in[7];
  float* out = (float*)d_out;

  const size_t XGB   = (size_t)TCH * 16 * 8 * 3 * 64 * 16;  // 100,663,296 B
  const size_t HLB   = (size_t)BB * HH * 4;                 // 262,144 B
  const size_t BTB   = (size_t)GG * 4;                      // 3,072 B
  if (ws_size < XGB + HLB + BTB) return;                    // need ~96.3 MB scratch

  unsigned short* xg = (unsigned short*)d_ws;
  float* hlast = (float*)((char*)d_ws + XGB);
  float* btot  = (float*)((char*)d_ws + XGB + HLB);

  k_btot<<<3, 256, 0, stream>>>(bih, bhh, btot);
  for (int c = 0; c < NCH; ++c) {
    k_xg  <<<TCH, 512, 0, stream>>>(x, Wih, btot, xg, c * TCH);
    k_scan<<<16,  512, 0, stream>>>(Whh, bhh, alp, xg, hlast, c * TCH);
  }
  k_out<<<64, 256, 0, stream>>>(hlast, fcw, fcb, out);
}